// Round 3
// baseline (317.807 us; speedup 1.0000x reference)
//
#include <hip/hip_runtime.h>

// SheafConnectionLayer: out = x; for each edge-dir i in [0,2E):
//   i<E  : g=src[e], s=dst[e]  (e=i)
//   i>=E : g=dst[e], s=src[e]  (e=i-E)
//   m = T[i] @ x[g] - x[s]
//   out[s] += (alpha * softplus(raw_w[i]) / max(deg[s],1)) * m
//
// Memory-bound on the single streaming read of T (819 MB). 16 lanes per
// edge-dir: lane d computes output dim d, reading T row d as 4x float4.
// T and raw_w are read exactly once -> nontemporal (nt) loads so the
// stream doesn't flush the 4 MiB/XCD L2 that x/out/ei/deg want to live in.

static constexpr int DD = 16;

typedef float f4 __attribute__((ext_vector_type(4)));

__global__ __launch_bounds__(256) void sheaf_edges(
    const float* __restrict__ x,
    const int*   __restrict__ ei,     // [2*E] : src rows then dst rows
    const float* __restrict__ deg,    // [N]
    const float* __restrict__ T,      // [2E][16][16]
    const float* __restrict__ raw_w,  // [2E]
    const float* __restrict__ alpha_p,// [1]
    float*       __restrict__ out,    // [N][16], pre-initialized to x
    int E, int E2)
{
    const float alpha = alpha_p[0];
    const int d = threadIdx.x & 15;                           // output dim
    const int group0  = (blockIdx.x * blockDim.x + threadIdx.x) >> 4;
    const int gstride = (gridDim.x * blockDim.x) >> 4;

    for (int i = group0; i < E2; i += gstride) {
        const int e = (i < E) ? i : (i - E);
        const int a = ei[e];          // src[e]
        const int b = ei[E + e];      // dst[e]
        const int g = (i < E) ? a : b;    // gather node
        const int s = (i < E) ? b : a;    // scatter node

        // T row for output dim d: 16 contiguous floats = 4x float4 (64B aligned)
        // Streamed once -> nontemporal, keep L2 clean for x/out/ei/deg.
        const f4* Tq = reinterpret_cast<const f4*>(
            T + (size_t)i * (DD * DD) + (size_t)d * DD);
        const f4 t0 = __builtin_nontemporal_load(Tq + 0);
        const f4 t1 = __builtin_nontemporal_load(Tq + 1);
        const f4 t2 = __builtin_nontemporal_load(Tq + 2);
        const f4 t3 = __builtin_nontemporal_load(Tq + 3);

        const float xg = x[(size_t)g * DD + d];
        const float xs = x[(size_t)s * DD + d];

        // dot = sum_k T[i][d][k] * x[g][k] via 16-wide shuffle broadcast
        float dot;
        dot  = t0.x * __shfl(xg,  0, 16);
        dot += t0.y * __shfl(xg,  1, 16);
        dot += t0.z * __shfl(xg,  2, 16);
        dot += t0.w * __shfl(xg,  3, 16);
        dot += t1.x * __shfl(xg,  4, 16);
        dot += t1.y * __shfl(xg,  5, 16);
        dot += t1.z * __shfl(xg,  6, 16);
        dot += t1.w * __shfl(xg,  7, 16);
        dot += t2.x * __shfl(xg,  8, 16);
        dot += t2.y * __shfl(xg,  9, 16);
        dot += t2.z * __shfl(xg, 10, 16);
        dot += t2.w * __shfl(xg, 11, 16);
        dot += t3.x * __shfl(xg, 12, 16);
        dot += t3.y * __shfl(xg, 13, 16);
        dot += t3.z * __shfl(xg, 14, 16);
        dot += t3.w * __shfl(xg, 15, 16);

        // softplus (numerically stable): max(x,0) + log1p(exp(-|x|))
        const float rw = __builtin_nontemporal_load(raw_w + i);
        const float w  = fmaxf(rw, 0.0f) + log1pf(__expf(-fabsf(rw)));
        const float c  = alpha * w / fmaxf(deg[s], 1.0f);

        atomicAdd(out + (size_t)s * DD + d, c * (dot - xs));
    }
}

extern "C" void kernel_launch(void* const* d_in, const int* in_sizes, int n_in,
                              void* d_out, int out_size, void* d_ws, size_t ws_size,
                              hipStream_t stream) {
    const float* x       = (const float*)d_in[0];
    const int*   ei      = (const int*)  d_in[1];
    const float* deg     = (const float*)d_in[2];
    const float* T       = (const float*)d_in[3];
    const float* raw_w   = (const float*)d_in[4];
    const float* alpha_p = (const float*)d_in[5];
    float* out = (float*)d_out;

    const int E  = in_sizes[1] / 2;   // edge_index is (2, E)
    const int E2 = 2 * E;             // total edge-directions

    // out = x  (deterministic re-init every call; graph-capture safe)
    hipMemcpyAsync(out, x, sizeof(float) * (size_t)out_size,
                   hipMemcpyDeviceToDevice, stream);

    const int threads = 256;
    const int blocks  = 2048;         // ~8 blocks/CU, grid-stride over 2E
    sheaf_edges<<<blocks, threads, 0, stream>>>(x, ei, deg, T, raw_w, alpha_p,
                                                out, E, E2);
}

// Round 4
// 157.167 us; speedup vs baseline: 2.0221x; 2.0221x over previous
//
#include <hip/hip_runtime.h>

// SheafConnectionLayer: out = x; for each edge-dir i in [0,2E):
//   i<E  : g=src[e], s=dst[e]  (e=i)
//   i>=E : g=dst[e], s=src[e]  (e=i-E)
//   m = T[i] @ x[g] - x[s]
//   out[s] += (alpha * softplus(raw_w[i]) / max(deg[s],1)) * m
//
// BW-bound on the one-shot 819 MB T stream. Key design: each 16-lane group
// reads its 1KB T tile in 4 instructions of 256B fully-contiguous,
// fully-used data (lane d, instr j -> 16B at tile + j*256 + d*16). Every T
// byte is touched exactly once by exactly one instruction, so T is read
// with nontemporal (evict-first) loads, keeping L2/L3 residency for the
// irregular working set (x gathers, out atomics, deg) -> no HBM refetch
// amplification on those.
//
// Lane d holds T rows {4j + (d>>2)} x cols [4(d&3) .. +3]. Partial dots are
// completed by a 2-step shfl_xor (1,2) within each aligned 4-lane cluster;
// lane d then owns output row r_out = 4*(d&3) + (d>>2) (transpose perm —
// the 16 lanes still cover one full 64B node line for xs load + atomic).

static constexpr int DD = 16;

typedef float f4 __attribute__((ext_vector_type(4)));

__global__ __launch_bounds__(256) void sheaf_edges(
    const float* __restrict__ x,
    const int*   __restrict__ ei,     // [2*E] : src rows then dst rows
    const float* __restrict__ deg,    // [N]
    const float* __restrict__ T,      // [2E][16][16]
    const float* __restrict__ raw_w,  // [2E]
    const float* __restrict__ alpha_p,// [1]
    float*       __restrict__ out,    // [N][16], pre-initialized to x
    int E, int E2)
{
    const float alpha = alpha_p[0];
    const int lane16 = threadIdx.x & 15;
    const int q   = lane16 >> 2;         // row offset within each quad (0..3)
    const int cc  = (lane16 & 3) << 2;   // col chunk base (0,4,8,12)
    const int sel = lane16 & 3;
    const int r_out = cc + q;            // output row this lane owns
    const int group0  = (blockIdx.x * blockDim.x + threadIdx.x) >> 4;
    const int gstride = (gridDim.x * blockDim.x) >> 4;

    for (int i = group0; i < E2; i += gstride) {
        const int e = (i < E) ? i : (i - E);
        const int a = ei[e];          // src[e]
        const int b = ei[E + e];      // dst[e]
        const int g = (i < E) ? a : b;    // gather node
        const int s = (i < E) ? b : a;    // scatter node

        // T tile (1KB): 4x 16B per lane, each byte read exactly once.
        const f4* Tt = reinterpret_cast<const f4*>(T + (size_t)i * 256) + lane16;
        const f4 m0 = __builtin_nontemporal_load(Tt +  0);   // rows  0+q
        const f4 m1 = __builtin_nontemporal_load(Tt + 16);   // rows  4+q
        const f4 m2 = __builtin_nontemporal_load(Tt + 32);   // rows  8+q
        const f4 m3 = __builtin_nontemporal_load(Tt + 48);   // rows 12+q
        // m_j[u] = T[i][4j+q][cc+u]

        // x[g] col chunk: one aligned float4, 4-way duplicated across lanes
        const f4 xg = *reinterpret_cast<const f4*>(x + (size_t)g * DD + cc);

        float p0 = m0.x*xg.x + m0.y*xg.y + m0.z*xg.z + m0.w*xg.w;
        float p1 = m1.x*xg.x + m1.y*xg.y + m1.z*xg.z + m1.w*xg.w;
        float p2 = m2.x*xg.x + m2.y*xg.y + m2.z*xg.z + m2.w*xg.w;
        float p3 = m3.x*xg.x + m3.y*xg.y + m3.z*xg.z + m3.w*xg.w;

        // complete dots across the 4 col-chunks (aligned 4-lane cluster)
        p0 += __shfl_xor(p0, 1);  p0 += __shfl_xor(p0, 2);
        p1 += __shfl_xor(p1, 1);  p1 += __shfl_xor(p1, 2);
        p2 += __shfl_xor(p2, 1);  p2 += __shfl_xor(p2, 2);
        p3 += __shfl_xor(p3, 1);  p3 += __shfl_xor(p3, 2);
        // lane holds dot[4j+q] in p_j; it owns r_out = 4*sel+q -> p_sel
        const float dot = (sel == 0) ? p0 : (sel == 1) ? p1
                        : (sel == 2) ? p2 : p3;

        const float xs = x[(size_t)s * DD + r_out];

        // softplus (numerically stable): max(x,0) + log1p(exp(-|x|))
        const float rw = raw_w[i];
        const float w  = fmaxf(rw, 0.0f) + log1pf(__expf(-fabsf(rw)));
        const float c  = alpha * w / fmaxf(deg[s], 1.0f);

        atomicAdd(out + (size_t)s * DD + r_out, c * (dot - xs));
    }
}

extern "C" void kernel_launch(void* const* d_in, const int* in_sizes, int n_in,
                              void* d_out, int out_size, void* d_ws, size_t ws_size,
                              hipStream_t stream) {
    const float* x       = (const float*)d_in[0];
    const int*   ei      = (const int*)  d_in[1];
    const float* deg     = (const float*)d_in[2];
    const float* T       = (const float*)d_in[3];
    const float* raw_w   = (const float*)d_in[4];
    const float* alpha_p = (const float*)d_in[5];
    float* out = (float*)d_out;

    const int E  = in_sizes[1] / 2;   // edge_index is (2, E)
    const int E2 = 2 * E;             // total edge-directions

    // out = x  (deterministic re-init every call; graph-capture safe)
    hipMemcpyAsync(out, x, sizeof(float) * (size_t)out_size,
                   hipMemcpyDeviceToDevice, stream);

    const int threads = 256;
    const int blocks  = 2048;         // grid-stride over 2E edge-directions
    sheaf_edges<<<blocks, threads, 0, stream>>>(x, ei, deg, T, raw_w, alpha_p,
                                                out, E, E2);
}

// Round 6
// 151.824 us; speedup vs baseline: 2.0933x; 1.0352x over previous
//
#include <hip/hip_runtime.h>

// SheafConnectionLayer: out = x; for each edge e (both directions together):
//   fwd: m = T[e]   @ x[a] - x[b], scatter to b, weight softplus(raw_w[e])
//   rev: m = T[E+e] @ x[b] - x[a], scatter to a, weight softplus(raw_w[E+e])
//   out[s] += (alpha * w / max(deg[s],1)) * m
//
// BW-bound on the one-shot 819 MB T stream. Each 16-lane group reads each
// 1KB T tile as 4 instructions x 256B fully-contiguous fully-used data
// (lane d, instr j -> 16B at tile + j*256 + d*16); every T byte touched
// exactly once -> nontemporal loads keep L2/L3 for x/out/ei/deg.
//
// Both directions of an edge share one iteration: 8 nt T loads (2KB)
// batched up-front for MLP; the x[a]/x[b] float4 gathers serve as BOTH the
// matvec operand of one direction and the x_s subtrahend of the other
// (r_out = cc+q lies in the lane's own col chunk, so xs = chunk[q]).
//
// out=x init is a dedicated kernel (NOT hipMemcpyAsync): a captured D2D
// memcpy node rides the SDMA/blit engine and its edge to the kernel node
// proved unreliable under graph replay (round 5: post-timing absmax 3.17 ==
// |x| magnitude == lost init). Kernel->kernel stream order is solid.

static constexpr int DD = 16;

typedef float f4 __attribute__((ext_vector_type(4)));

__global__ __launch_bounds__(256) void init_out(
    const f4* __restrict__ x4, f4* __restrict__ out4, int n4)
{
    const int i = blockIdx.x * blockDim.x + threadIdx.x;
    if (i < n4) out4[i] = x4[i];
}

__global__ __launch_bounds__(256) void sheaf_edges(
    const float* __restrict__ x,
    const int*   __restrict__ ei,     // [2*E] : src rows then dst rows
    const float* __restrict__ deg,    // [N]
    const float* __restrict__ T,      // [2E][16][16]
    const float* __restrict__ raw_w,  // [2E]
    const float* __restrict__ alpha_p,// [1]
    float*       __restrict__ out,    // [N][16], pre-initialized to x
    int E)
{
    const float alpha = alpha_p[0];
    const int lane16 = threadIdx.x & 15;
    const int q   = lane16 >> 2;         // row offset within each quad (0..3)
    const int cc  = (lane16 & 3) << 2;   // col chunk base (0,4,8,12)
    const int sel = lane16 & 3;
    const int r_out = cc + q;            // output row this lane owns
    const int group0  = (blockIdx.x * blockDim.x + threadIdx.x) >> 4;
    const int gstride = (gridDim.x * blockDim.x) >> 4;

    for (int e = group0; e < E; e += gstride) {
        // Batch all 8 nt T loads (fwd tile + rev tile) up-front: 2KB of
        // independent stream reads in flight per group iteration.
        const f4* Tf = reinterpret_cast<const f4*>(T + (size_t)e * 256) + lane16;
        const f4* Tr = reinterpret_cast<const f4*>(T + ((size_t)E + e) * 256) + lane16;
        const f4 f0 = __builtin_nontemporal_load(Tf +  0);
        const f4 f1 = __builtin_nontemporal_load(Tf + 16);
        const f4 f2 = __builtin_nontemporal_load(Tf + 32);
        const f4 f3 = __builtin_nontemporal_load(Tf + 48);
        const f4 r0 = __builtin_nontemporal_load(Tr +  0);
        const f4 r1 = __builtin_nontemporal_load(Tr + 16);
        const f4 r2 = __builtin_nontemporal_load(Tr + 32);
        const f4 r3 = __builtin_nontemporal_load(Tr + 48);

        const int a = ei[e];          // src[e]: rev scatter / fwd gather
        const int b = ei[E + e];      // dst[e]: fwd scatter / rev gather
        const f4 xa = *reinterpret_cast<const f4*>(x + (size_t)a * DD + cc);
        const f4 xb = *reinterpret_cast<const f4*>(x + (size_t)b * DD + cc);

        // forward: T[e] @ x[a]
        float p0 = f0.x*xa.x + f0.y*xa.y + f0.z*xa.z + f0.w*xa.w;
        float p1 = f1.x*xa.x + f1.y*xa.y + f1.z*xa.z + f1.w*xa.w;
        float p2 = f2.x*xa.x + f2.y*xa.y + f2.z*xa.z + f2.w*xa.w;
        float p3 = f3.x*xa.x + f3.y*xa.y + f3.z*xa.z + f3.w*xa.w;
        p0 += __shfl_xor(p0, 1);  p0 += __shfl_xor(p0, 2);
        p1 += __shfl_xor(p1, 1);  p1 += __shfl_xor(p1, 2);
        p2 += __shfl_xor(p2, 1);  p2 += __shfl_xor(p2, 2);
        p3 += __shfl_xor(p3, 1);  p3 += __shfl_xor(p3, 2);
        const float dotF = (sel == 0) ? p0 : (sel == 1) ? p1
                         : (sel == 2) ? p2 : p3;

        // reverse: T[E+e] @ x[b]
        float s0 = r0.x*xb.x + r0.y*xb.y + r0.z*xb.z + r0.w*xb.w;
        float s1 = r1.x*xb.x + r1.y*xb.y + r1.z*xb.z + r1.w*xb.w;
        float s2 = r2.x*xb.x + r2.y*xb.y + r2.z*xb.z + r2.w*xb.w;
        float s3 = r3.x*xb.x + r3.y*xb.y + r3.z*xb.z + r3.w*xb.w;
        s0 += __shfl_xor(s0, 1);  s0 += __shfl_xor(s0, 2);
        s1 += __shfl_xor(s1, 1);  s1 += __shfl_xor(s1, 2);
        s2 += __shfl_xor(s2, 1);  s2 += __shfl_xor(s2, 2);
        s3 += __shfl_xor(s3, 1);  s3 += __shfl_xor(s3, 2);
        const float dotR = (sel == 0) ? s0 : (sel == 1) ? s1
                         : (sel == 2) ? s2 : s3;

        // x_s[r_out] is component q of the other direction's gather chunk
        const float xsF = (q == 0) ? xb.x : (q == 1) ? xb.y
                        : (q == 2) ? xb.z : xb.w;
        const float xsR = (q == 0) ? xa.x : (q == 1) ? xa.y
                        : (q == 2) ? xa.z : xa.w;

        // softplus (numerically stable): max(x,0) + log1p(exp(-|x|))
        const float rwF = raw_w[e];
        const float rwR = raw_w[E + e];
        const float wF  = fmaxf(rwF, 0.0f) + log1pf(__expf(-fabsf(rwF)));
        const float wR  = fmaxf(rwR, 0.0f) + log1pf(__expf(-fabsf(rwR)));
        const float cF  = alpha * wF / fmaxf(deg[b], 1.0f);
        const float cR  = alpha * wR / fmaxf(deg[a], 1.0f);

        atomicAdd(out + (size_t)b * DD + r_out, cF * (dotF - xsF));
        atomicAdd(out + (size_t)a * DD + r_out, cR * (dotR - xsR));
    }
}

extern "C" void kernel_launch(void* const* d_in, const int* in_sizes, int n_in,
                              void* d_out, int out_size, void* d_ws, size_t ws_size,
                              hipStream_t stream) {
    const float* x       = (const float*)d_in[0];
    const int*   ei      = (const int*)  d_in[1];
    const float* deg     = (const float*)d_in[2];
    const float* T       = (const float*)d_in[3];
    const float* raw_w   = (const float*)d_in[4];
    const float* alpha_p = (const float*)d_in[5];
    float* out = (float*)d_out;

    const int E = in_sizes[1] / 2;    // edge_index is (2, E)

    // out = x via kernel (same-stream kernel->kernel ordering is reliable
    // under graph capture; captured SDMA memcpy nodes were not).
    const int n4 = out_size / 4;      // out_size = N*16, divisible by 4
    init_out<<<(n4 + 255) / 256, 256, 0, stream>>>(
        reinterpret_cast<const f4*>(x), reinterpret_cast<f4*>(out), n4);

    const int threads = 256;
    const int blocks  = 2048;         // grid-stride over E edge pairs
    sheaf_edges<<<blocks, threads, 0, stream>>>(x, ei, deg, T, raw_w, alpha_p,
                                                out, E);
}

// Round 8
// 149.530 us; speedup vs baseline: 2.1254x; 1.0153x over previous
//
#include <hip/hip_runtime.h>

// SheafConnectionLayer: out = x; for each edge e (both directions):
//   fwd: m = T[e]   @ x[a] - x[b], scatter to b, weight softplus(raw_w[e])
//   rev: m = T[E+e] @ x[b] - x[a], scatter to a, weight softplus(raw_w[E+e])
//   out[s] += (alpha * w / max(deg[s],1)) * m
//
// BW-bound on the one-shot 819 MB T stream. Each 16-lane group reads each
// 1KB T tile as 4 instructions x 256B fully-contiguous fully-used data
// (lane d, instr j -> 16B at tile + j*256 + d*16); every T byte touched
// exactly once -> nontemporal loads keep L2/L3 for x/out/ei/deg.
//
// Round 7: 2-edge batching. Each group handles edges {2p, 2p+1}, both
// directions: 16 nt T loads (4KB) issued up-front per iteration for max
// memory-level parallelism; ei reads become two aligned int2 loads; loop
// overhead halves. x[a]/x[b] float4 gathers double as the matvec operand
// of one direction and the x_s subtrahend of the other (r_out = cc+q lies
// in the lane's own col chunk, so xs = chunk[q]).
//
// out=x init is a dedicated kernel (NOT hipMemcpyAsync): a captured D2D
// memcpy node rides the SDMA path and its edge to the kernel node proved
// unreliable under graph replay (round 5: post-timing absmax 3.17 == |x|).

static constexpr int DD = 16;

typedef float f4 __attribute__((ext_vector_type(4)));

__global__ __launch_bounds__(256) void init_out(
    const f4* __restrict__ x4, f4* __restrict__ out4, int n4)
{
    const int i = blockIdx.x * blockDim.x + threadIdx.x;
    if (i < n4) out4[i] = x4[i];
}

__device__ __forceinline__ float dot_rows(
    const f4 m0, const f4 m1, const f4 m2, const f4 m3,
    const f4 xg, const int sel)
{
    float p0 = m0.x*xg.x + m0.y*xg.y + m0.z*xg.z + m0.w*xg.w;
    float p1 = m1.x*xg.x + m1.y*xg.y + m1.z*xg.z + m1.w*xg.w;
    float p2 = m2.x*xg.x + m2.y*xg.y + m2.z*xg.z + m2.w*xg.w;
    float p3 = m3.x*xg.x + m3.y*xg.y + m3.z*xg.z + m3.w*xg.w;
    p0 += __shfl_xor(p0, 1);  p0 += __shfl_xor(p0, 2);
    p1 += __shfl_xor(p1, 1);  p1 += __shfl_xor(p1, 2);
    p2 += __shfl_xor(p2, 1);  p2 += __shfl_xor(p2, 2);
    p3 += __shfl_xor(p3, 1);  p3 += __shfl_xor(p3, 2);
    return (sel == 0) ? p0 : (sel == 1) ? p1 : (sel == 2) ? p2 : p3;
}

__device__ __forceinline__ float softplus_f(const float v)
{
    return fmaxf(v, 0.0f) + log1pf(__expf(-fabsf(v)));
}

__device__ __forceinline__ float comp_q(const f4 v, const int q)
{
    return (q == 0) ? v.x : (q == 1) ? v.y : (q == 2) ? v.z : v.w;
}

__global__ __launch_bounds__(256) void sheaf_edges(
    const float* __restrict__ x,
    const int*   __restrict__ ei,     // [2*E] : src rows then dst rows
    const float* __restrict__ deg,    // [N]
    const float* __restrict__ T,      // [2E][16][16]
    const float* __restrict__ raw_w,  // [2E]
    const float* __restrict__ alpha_p,// [1]
    float*       __restrict__ out,    // [N][16], pre-initialized to x
    int E)
{
    const float alpha = alpha_p[0];
    const int lane16 = threadIdx.x & 15;
    const int q   = lane16 >> 2;         // row offset within each quad (0..3)
    const int cc  = (lane16 & 3) << 2;   // col chunk base (0,4,8,12)
    const int sel = lane16 & 3;
    const int r_out = cc + q;            // output row this lane owns
    const int group0  = (blockIdx.x * blockDim.x + threadIdx.x) >> 4;
    const int gstride = (gridDim.x * blockDim.x) >> 4;
    const int npairs  = E >> 1;

    for (int p = group0; p < npairs; p += gstride) {
        const int eA = 2 * p;            // edge pair {eA, eA+1}

        // 16 nt T loads (4 tiles x 4 chunks = 4KB) batched up-front.
        const f4* TfA = reinterpret_cast<const f4*>(T + (size_t)eA * 256) + lane16;
        const f4* TrA = reinterpret_cast<const f4*>(T + ((size_t)E + eA) * 256) + lane16;
        const f4 fA0 = __builtin_nontemporal_load(TfA +  0);
        const f4 fA1 = __builtin_nontemporal_load(TfA + 16);
        const f4 fA2 = __builtin_nontemporal_load(TfA + 32);
        const f4 fA3 = __builtin_nontemporal_load(TfA + 48);
        const f4 fB0 = __builtin_nontemporal_load(TfA + 64);   // tile eA+1
        const f4 fB1 = __builtin_nontemporal_load(TfA + 80);
        const f4 fB2 = __builtin_nontemporal_load(TfA + 96);
        const f4 fB3 = __builtin_nontemporal_load(TfA + 112);
        const f4 rA0 = __builtin_nontemporal_load(TrA +  0);
        const f4 rA1 = __builtin_nontemporal_load(TrA + 16);
        const f4 rA2 = __builtin_nontemporal_load(TrA + 32);
        const f4 rA3 = __builtin_nontemporal_load(TrA + 48);
        const f4 rB0 = __builtin_nontemporal_load(TrA + 64);   // tile E+eA+1
        const f4 rB1 = __builtin_nontemporal_load(TrA + 80);
        const f4 rB2 = __builtin_nontemporal_load(TrA + 96);
        const f4 rB3 = __builtin_nontemporal_load(TrA + 112);

        // edge endpoints: int2 (eA even -> 8B aligned; E even)
        const int2 aa = *reinterpret_cast<const int2*>(ei + eA);      // src
        const int2 bb = *reinterpret_cast<const int2*>(ei + E + eA);  // dst
        const f4 xa0 = *reinterpret_cast<const f4*>(x + (size_t)aa.x * DD + cc);
        const f4 xb0 = *reinterpret_cast<const f4*>(x + (size_t)bb.x * DD + cc);
        const f4 xa1 = *reinterpret_cast<const f4*>(x + (size_t)aa.y * DD + cc);
        const f4 xb1 = *reinterpret_cast<const f4*>(x + (size_t)bb.y * DD + cc);

        const float dotF0 = dot_rows(fA0, fA1, fA2, fA3, xa0, sel);
        const float dotR0 = dot_rows(rA0, rA1, rA2, rA3, xb0, sel);
        const float dotF1 = dot_rows(fB0, fB1, fB2, fB3, xa1, sel);
        const float dotR1 = dot_rows(rB0, rB1, rB2, rB3, xb1, sel);

        const float wF0 = softplus_f(raw_w[eA]);
        const float wF1 = softplus_f(raw_w[eA + 1]);
        const float wR0 = softplus_f(raw_w[E + eA]);
        const float wR1 = softplus_f(raw_w[E + eA + 1]);

        const float cF0 = alpha * wF0 / fmaxf(deg[bb.x], 1.0f);
        const float cR0 = alpha * wR0 / fmaxf(deg[aa.x], 1.0f);
        const float cF1 = alpha * wF1 / fmaxf(deg[bb.y], 1.0f);
        const float cR1 = alpha * wR1 / fmaxf(deg[aa.y], 1.0f);

        atomicAdd(out + (size_t)bb.x * DD + r_out, cF0 * (dotF0 - comp_q(xb0, q)));
        atomicAdd(out + (size_t)aa.x * DD + r_out, cR0 * (dotR0 - comp_q(xa0, q)));
        atomicAdd(out + (size_t)bb.y * DD + r_out, cF1 * (dotF1 - comp_q(xb1, q)));
        atomicAdd(out + (size_t)aa.y * DD + r_out, cR1 * (dotR1 - comp_q(xa1, q)));
    }

    // odd-E tail (not hit for E=400000, kept for correctness)
    if ((E & 1) && group0 == 0) {
        const int e = E - 1;
        const f4* Tf = reinterpret_cast<const f4*>(T + (size_t)e * 256) + lane16;
        const f4* Tr = reinterpret_cast<const f4*>(T + ((size_t)E + e) * 256) + lane16;
        const f4 f0 = Tf[0], f1 = Tf[16], f2 = Tf[32], f3 = Tf[48];
        const f4 r0 = Tr[0], r1 = Tr[16], r2 = Tr[32], r3 = Tr[48];
        const int a = ei[e], b = ei[E + e];
        const f4 xa = *reinterpret_cast<const f4*>(x + (size_t)a * DD + cc);
        const f4 xb = *reinterpret_cast<const f4*>(x + (size_t)b * DD + cc);
        const float dotF = dot_rows(f0, f1, f2, f3, xa, sel);
        const float dotR = dot_rows(r0, r1, r2, r3, xb, sel);
        const float cF = alpha * softplus_f(raw_w[e])     / fmaxf(deg[b], 1.0f);
        const float cR = alpha * softplus_f(raw_w[E + e]) / fmaxf(deg[a], 1.0f);
        atomicAdd(out + (size_t)b * DD + r_out, cF * (dotF - comp_q(xb, q)));
        atomicAdd(out + (size_t)a * DD + r_out, cR * (dotR - comp_q(xa, q)));
    }
}

extern "C" void kernel_launch(void* const* d_in, const int* in_sizes, int n_in,
                              void* d_out, int out_size, void* d_ws, size_t ws_size,
                              hipStream_t stream) {
    const float* x       = (const float*)d_in[0];
    const int*   ei      = (const int*)  d_in[1];
    const float* deg     = (const float*)d_in[2];
    const float* T       = (const float*)d_in[3];
    const float* raw_w   = (const float*)d_in[4];
    const float* alpha_p = (const float*)d_in[5];
    float* out = (float*)d_out;

    const int E = in_sizes[1] / 2;    // edge_index is (2, E)

    // out = x via kernel (same-stream kernel->kernel ordering is reliable
    // under graph capture; captured SDMA memcpy nodes were not).
    const int n4 = out_size / 4;      // out_size = N*16, divisible by 4
    init_out<<<(n4 + 255) / 256, 256, 0, stream>>>(
        reinterpret_cast<const f4*>(x), reinterpret_cast<f4*>(out), n4);

    const int threads = 256;
    const int blocks  = 2048;         // grid-stride over E/2 edge pairs
    sheaf_edges<<<blocks, threads, 0, stream>>>(x, ei, deg, T, raw_w, alpha_p,
                                                out, E);
}